// Round 13
// baseline (287.962 us; speedup 1.0000x reference)
//
#include <hip/hip_runtime.h>

#define D 128
#define RB 256          // rows per bucket
#define NBKMAX 256      // max buckets (N <= 65536)
#define CH 256          // edge chunks
#define LDSREC 6400     // max records staged per chunk

typedef __attribute__((ext_vector_type(4))) float f32x4;
typedef __attribute__((ext_vector_type(8))) short bf16x8;

__device__ __forceinline__ unsigned short bf16r(float f) {
    unsigned b = __float_as_uint(f);
    return (unsigned short)((b + 0x7FFFu + ((b >> 16) & 1u)) >> 16);
}

// ---------------- setup: fp32 WT (fallback) + bf16 Wb (MFMA path) -----------------
__global__ __launch_bounds__(256) void setup_weights(
    const float* __restrict__ Uky, const float* __restrict__ Ukx,
    const float* __restrict__ Vky, const float* __restrict__ Vkx,
    const float* __restrict__ Wkx, const float* __restrict__ Vkx_b,
    const float* __restrict__ Wkx_b,
    float* __restrict__ UkyT, float* __restrict__ UkxT,
    float* __restrict__ VkyT, float* __restrict__ WcT,
    unsigned short* __restrict__ UkyB, unsigned short* __restrict__ UkxB,
    unsigned short* __restrict__ VkyB, unsigned short* __restrict__ WcB,
    float* __restrict__ bc)
{
    const int m = blockIdx.x;
    if (m < 4) {
        const float* src = (m == 0) ? Uky : (m == 1) ? Ukx : (m == 2) ? Vky : nullptr;
        float* dst = (m == 0) ? UkyT : (m == 1) ? UkxT : (m == 2) ? VkyT : WcT;
        for (int i = threadIdx.x; i < D * D; i += 256) {
            int k = i >> 7, d = i & 127;
            float v;
            if (m == 3) v = Vkx[d * D + k] - 2.0f * Wkx[d * D + k];
            else        v = src[d * D + k];
            dst[i] = v;
        }
        if (m == 3 && threadIdx.x < D)
            bc[threadIdx.x] = Vkx_b[threadIdx.x] - 2.0f * Wkx_b[threadIdx.x];
    } else {
        const int mm = m - 4;
        const float* src = (mm == 0) ? Uky : (mm == 1) ? Ukx : (mm == 2) ? Vky : nullptr;
        unsigned short* dst = (mm == 0) ? UkyB : (mm == 1) ? UkxB : (mm == 2) ? VkyB : WcB;
        for (int i = threadIdx.x; i < D * D; i += 256) {
            float v;
            if (mm == 3) v = Vkx[i] - 2.0f * Wkx[i];
            else         v = src[i];
            dst[i] = bf16r(v);
        }
    }
}

// ---------------- MFMA GEMM (round 10) ----------------
template <int EPI, int OB16>
__global__ __launch_bounds__(256) void gemm_mfma(
    const float* __restrict__ X, const unsigned short* __restrict__ Wb,
    const float* __restrict__ bias, const float* __restrict__ colvec,
    const float* __restrict__ spout, const float* __restrict__ scal,
    float* __restrict__ out, int N)
{
    __shared__ __align__(16) unsigned short Xs[64 * 128];
    const int t = threadIdx.x;
    const int block_row = blockIdx.x * 64;

#pragma unroll
    for (int i = 0; i < 8; ++i) {
        int f = t + i * 256;
        int r = f >> 5;
        int k4 = (f & 31) << 2;
        float4 g = make_float4(0.f, 0.f, 0.f, 0.f);
        int row = block_row + r;
        if (row < N) g = *reinterpret_cast<const float4*>(&X[(size_t)row * D + k4]);
        ushort4 h;
        h.x = bf16r(g.x); h.y = bf16r(g.y); h.z = bf16r(g.z); h.w = bf16r(g.w);
        unsigned byte = (unsigned)(k4 * 2) ^ ((unsigned)(r & 7) << 4);
        *reinterpret_cast<ushort4*>((char*)Xs + r * 256 + byte) = h;
    }
    __syncthreads();

    const int w  = t >> 6;
    const int l  = t & 63;
    const int lr = l & 15;
    const int lq = l >> 4;

    f32x4 acc[8];
#pragma unroll
    for (int nt = 0; nt < 8; ++nt) acc[nt] = (f32x4)(0.f);

    const int arow = w * 16 + lr;

#pragma unroll
    for (int kc = 0; kc < 4; ++kc) {
        unsigned abyte = ((unsigned)(kc * 64 + lq * 16)) ^ ((unsigned)(arow & 7) << 4);
        bf16x8 a = *reinterpret_cast<const bf16x8*>((const char*)Xs + arow * 256 + abyte);
#pragma unroll
        for (int nt = 0; nt < 8; ++nt) {
            bf16x8 b = *reinterpret_cast<const bf16x8*>(
                &Wb[(size_t)(nt * 16 + lr) * D + kc * 32 + lq * 8]);
            acc[nt] = __builtin_amdgcn_mfma_f32_16x16x32_bf16(a, b, acc[nt], 0, 0, 0);
        }
    }

    const float sc = (EPI == 0) ? 0.f : scal[0];
    float bs[8];
#pragma unroll
    for (int nt = 0; nt < 8; ++nt) bs[nt] = bias[nt * 16 + lr];

#pragma unroll
    for (int r = 0; r < 4; ++r) {
        const int row = block_row + w * 16 + lq * 4 + r;
        if (row >= N) continue;
        const float cv = (EPI == 0) ? 0.f : colvec[row];
#pragma unroll
        for (int nt = 0; nt < 8; ++nt) {
            const int col = nt * 16 + lr;
            float res = acc[nt][r] + bs[nt];
            if (EPI == 1) {
                float sp = spout[(size_t)row * D + col];
                res = fmaxf(res - sc * (cv - sp), 0.f);
            } else if (EPI == 2) {
                float sp = spout[(size_t)row * D + col];
                res = fmaxf(res - sc * (cv + sp), 0.f);
            }
            if (OB16) ((unsigned short*)out)[(size_t)row * D + col] = bf16r(res);
            else      out[(size_t)row * D + col] = res;
        }
    }
}

// ---------------- fused x_new + zx GEMM ----------------
// pass 1: x_new = relu(X@Ukx^T + b - tau*(c - at_uy)) -> out fp32 (in place over spout)
// pass 2: zx = x_new @ Wc^T + bc -> out2 bf16   (x_new tile re-staged via LDS)
__global__ __launch_bounds__(256) void gemm_mfma_xz(
    const float* __restrict__ X, const unsigned short* __restrict__ Wb,
    const float* __restrict__ bias, const float* __restrict__ colvec,
    const float* __restrict__ spout, const float* __restrict__ scal,
    float* __restrict__ out,
    const unsigned short* __restrict__ Wb2, const float* __restrict__ bias2,
    unsigned short* __restrict__ out2, int N)
{
    __shared__ __align__(16) unsigned short Xs[64 * 128];
    const int t = threadIdx.x;
    const int block_row = blockIdx.x * 64;

#pragma unroll
    for (int i = 0; i < 8; ++i) {
        int f = t + i * 256;
        int r = f >> 5;
        int k4 = (f & 31) << 2;
        float4 g = make_float4(0.f, 0.f, 0.f, 0.f);
        int row = block_row + r;
        if (row < N) g = *reinterpret_cast<const float4*>(&X[(size_t)row * D + k4]);
        ushort4 h;
        h.x = bf16r(g.x); h.y = bf16r(g.y); h.z = bf16r(g.z); h.w = bf16r(g.w);
        unsigned byte = (unsigned)(k4 * 2) ^ ((unsigned)(r & 7) << 4);
        *reinterpret_cast<ushort4*>((char*)Xs + r * 256 + byte) = h;
    }
    __syncthreads();

    const int w  = t >> 6;
    const int l  = t & 63;
    const int lr = l & 15;
    const int lq = l >> 4;
    const int arow = w * 16 + lr;

    f32x4 acc[8];
#pragma unroll
    for (int nt = 0; nt < 8; ++nt) acc[nt] = (f32x4)(0.f);

#pragma unroll
    for (int kc = 0; kc < 4; ++kc) {
        unsigned abyte = ((unsigned)(kc * 64 + lq * 16)) ^ ((unsigned)(arow & 7) << 4);
        bf16x8 a = *reinterpret_cast<const bf16x8*>((const char*)Xs + arow * 256 + abyte);
#pragma unroll
        for (int nt = 0; nt < 8; ++nt) {
            bf16x8 b = *reinterpret_cast<const bf16x8*>(
                &Wb[(size_t)(nt * 16 + lr) * D + kc * 32 + lq * 8]);
            acc[nt] = __builtin_amdgcn_mfma_f32_16x16x32_bf16(a, b, acc[nt], 0, 0, 0);
        }
    }
    __syncthreads();                     // all pass-1 A-reads done; Xs reusable

    const float sc = scal[0];
    float bs[8];
#pragma unroll
    for (int nt = 0; nt < 8; ++nt) bs[nt] = bias[nt * 16 + lr];

    // epilogue 1: write x_new (fp32) + stage bf16(x_new) into Xs for pass 2
#pragma unroll
    for (int r = 0; r < 4; ++r) {
        const int lrow = w * 16 + lq * 4 + r;
        const int row = block_row + lrow;
        const float cv = (row < N) ? colvec[row] : 0.f;
#pragma unroll
        for (int nt = 0; nt < 8; ++nt) {
            const int col = nt * 16 + lr;
            float res = 0.f;
            if (row < N) {
                float sp = spout[(size_t)row * D + col];
                res = fmaxf(acc[nt][r] + bs[nt] - sc * (cv - sp), 0.f);
                out[(size_t)row * D + col] = res;
            }
            unsigned byte = (unsigned)(col * 2) ^ ((unsigned)(lrow & 7) << 4);
            *reinterpret_cast<unsigned short*>((char*)Xs + lrow * 256 + byte) = bf16r(res);
        }
    }
    __syncthreads();

    // pass 2: zx = x_new @ Wc^T + bc -> bf16
#pragma unroll
    for (int nt = 0; nt < 8; ++nt) acc[nt] = (f32x4)(0.f);
#pragma unroll
    for (int kc = 0; kc < 4; ++kc) {
        unsigned abyte = ((unsigned)(kc * 64 + lq * 16)) ^ ((unsigned)(arow & 7) << 4);
        bf16x8 a = *reinterpret_cast<const bf16x8*>((const char*)Xs + arow * 256 + abyte);
#pragma unroll
        for (int nt = 0; nt < 8; ++nt) {
            bf16x8 b = *reinterpret_cast<const bf16x8*>(
                &Wb2[(size_t)(nt * 16 + lr) * D + kc * 32 + lq * 8]);
            acc[nt] = __builtin_amdgcn_mfma_f32_16x16x32_bf16(a, b, acc[nt], 0, 0, 0);
        }
    }
#pragma unroll
    for (int nt = 0; nt < 8; ++nt) bs[nt] = bias2[nt * 16 + lr];
#pragma unroll
    for (int r = 0; r < 4; ++r) {
        const int row = block_row + w * 16 + lq * 4 + r;
        if (row >= N) continue;
#pragma unroll
        for (int nt = 0; nt < 8; ++nt) {
            const int col = nt * 16 + lr;
            out2[(size_t)row * D + col] = bf16r(acc[nt][r] + bs[nt]);
        }
    }
}

// ---------------- fp32 GEMM (fallback path only) ----------------
template <int EPI>
__global__ __launch_bounds__(256) void gemm_v2(
    const float* __restrict__ X, const float* __restrict__ WT,
    const float* __restrict__ bias, const float* __restrict__ colvec,
    const float* __restrict__ spout, const float* __restrict__ scal,
    float* __restrict__ out, int N)
{
    __shared__ float Xsf[64][D + 4];
    __shared__ float Wt[64][D + 4];
    const int t = threadIdx.x;
    const int block_row = blockIdx.x * 64;

#pragma unroll
    for (int i = 0; i < 8; ++i) {
        int f = t + i * 256;
        int r = f >> 5;
        int k4 = (f & 31) << 2;
        float4 g = make_float4(0.f, 0.f, 0.f, 0.f);
        int row = block_row + r;
        if (row < N) g = *reinterpret_cast<const float4*>(&X[(size_t)row * D + k4]);
        *reinterpret_cast<float4*>(&Xsf[r][k4]) = g;
    }

    const int cg = t & 15;
    const int rp = t >> 4;
    const int r0 = rp * 4;
    const int c0 = cg * 4, c1 = 64 + cg * 4;
    float acc[4][8] = {{0.f}};

    for (int kb = 0; kb < D; kb += 64) {
        __syncthreads();
#pragma unroll
        for (int i = 0; i < 8; ++i) {
            int f = t + i * 256;
            int kk = f >> 5;
            int d4 = (f & 31) << 2;
            float4 g = *reinterpret_cast<const float4*>(&WT[(size_t)(kb + kk) * D + d4]);
            *reinterpret_cast<float4*>(&Wt[kk][d4]) = g;
        }
        __syncthreads();
#pragma unroll 2
        for (int k4 = 0; k4 < 64; k4 += 4) {
            float4 xr[4];
#pragma unroll
            for (int j = 0; j < 4; ++j)
                xr[j] = *reinterpret_cast<const float4*>(&Xsf[r0 + j][kb + k4]);
#pragma unroll
            for (int q = 0; q < 4; ++q) {
                const float4 w0 = *reinterpret_cast<const float4*>(&Wt[k4 + q][c0]);
                const float4 w1 = *reinterpret_cast<const float4*>(&Wt[k4 + q][c1]);
#pragma unroll
                for (int j = 0; j < 4; ++j) {
                    const float xv = (q == 0) ? xr[j].x : (q == 1) ? xr[j].y
                                   : (q == 2) ? xr[j].z : xr[j].w;
                    acc[j][0] += xv * w0.x; acc[j][1] += xv * w0.y;
                    acc[j][2] += xv * w0.z; acc[j][3] += xv * w0.w;
                    acc[j][4] += xv * w1.x; acc[j][5] += xv * w1.y;
                    acc[j][6] += xv * w1.z; acc[j][7] += xv * w1.w;
                }
            }
        }
    }

    const float sc = (EPI == 0) ? 0.f : scal[0];
    const float4 bias0 = *reinterpret_cast<const float4*>(&bias[c0]);
    const float4 bias1 = *reinterpret_cast<const float4*>(&bias[c1]);

#pragma unroll
    for (int j = 0; j < 4; ++j) {
        const int row = block_row + r0 + j;
        if (row >= N) continue;
        const float cv = (EPI == 0) ? 0.f : colvec[row];
#pragma unroll
        for (int h = 0; h < 2; ++h) {
            const int col = (h == 0) ? c0 : c1;
            const float4 bsv = (h == 0) ? bias0 : bias1;
            float4 res;
            res.x = acc[j][h * 4 + 0] + bsv.x;
            res.y = acc[j][h * 4 + 1] + bsv.y;
            res.z = acc[j][h * 4 + 2] + bsv.z;
            res.w = acc[j][h * 4 + 3] + bsv.w;
            if (EPI == 1) {
                float4 sp = *reinterpret_cast<const float4*>(&spout[(size_t)row * D + col]);
                res.x = fmaxf(res.x - sc * (cv - sp.x), 0.f);
                res.y = fmaxf(res.y - sc * (cv - sp.y), 0.f);
                res.z = fmaxf(res.z - sc * (cv - sp.z), 0.f);
                res.w = fmaxf(res.w - sc * (cv - sp.w), 0.f);
            } else if (EPI == 2) {
                float4 sp = *reinterpret_cast<const float4*>(&spout[(size_t)row * D + col]);
                res.x = fmaxf(res.x - sc * (cv + sp.x), 0.f);
                res.y = fmaxf(res.y - sc * (cv + sp.y), 0.f);
                res.z = fmaxf(res.z - sc * (cv + sp.z), 0.f);
                res.w = fmaxf(res.w - sc * (cv + sp.w), 0.f);
            }
            *reinterpret_cast<float4*>(&out[(size_t)row * D + col]) = res;
        }
    }
}

// ---------------- K1: per-chunk bucket histogram ----------------
__global__ __launch_bounds__(256) void hist_chunks(
    const int* __restrict__ rows, const int* __restrict__ cols,
    int* __restrict__ hR, int* __restrict__ hC, int nnz, int nbk, int ce)
{
    __shared__ int lh[NBKMAX];
    const int chunk = blockIdx.x;
    const bool isC = blockIdx.y;
    const int* idx = isC ? cols : rows;
    int* hout = (isC ? hC : hR) + (size_t)chunk * nbk;
    for (int i = threadIdx.x; i < nbk; i += 256) lh[i] = 0;
    __syncthreads();
    const int e0 = chunk * ce, e1 = min(nnz, e0 + ce);
    for (int e = e0 + threadIdx.x; e < e1; e += 256)
        atomicAdd(&lh[idx[e] >> 8], 1);
    __syncthreads();
    for (int i = threadIdx.x; i < nbk; i += 256) hout[i] = lh[i];
}

// ---------------- K2: bucket totals ----------------
__global__ __launch_bounds__(256) void bucket_tot(
    const int* __restrict__ hR, const int* __restrict__ hC,
    int* __restrict__ cntR, int* __restrict__ cntC, int nbk)
{
    const int b = blockIdx.x;
    const bool isC = blockIdx.y;
    const int* h = (isC ? hC : hR);
    __shared__ int s[256];
    int v = h[(size_t)threadIdx.x * nbk + b];
    s[threadIdx.x] = v;
    __syncthreads();
#pragma unroll
    for (int d = 128; d > 0; d >>= 1) {
        if (threadIdx.x < d) s[threadIdx.x] += s[threadIdx.x + d];
        __syncthreads();
    }
    if (threadIdx.x == 0) (isC ? cntC : cntR)[b] = s[0];
}

// ---------------- K3: bucket scan -> goff ----------------
__global__ __launch_bounds__(256) void scan_buckets(
    const int* __restrict__ cntR, const int* __restrict__ cntC,
    int* __restrict__ goffR, int* __restrict__ goffC, int nbk)
{
    const int* cnt = blockIdx.x ? cntC : cntR;
    int* goff = blockIdx.x ? goffC : goffR;
    __shared__ int s[256];
    const int t = threadIdx.x;
    int v = (t < nbk) ? cnt[t] : 0;
    s[t] = v;
    __syncthreads();
#pragma unroll
    for (int d = 1; d < 256; d <<= 1) {
        int tv = (t >= d) ? s[t - d] : 0;
        __syncthreads();
        s[t] += tv;
        __syncthreads();
    }
    if (t < nbk) goff[t] = s[t] - v;
}

// ---------------- K4: run starts ----------------
__global__ __launch_bounds__(256) void runstarts(
    const int* __restrict__ hR, const int* __restrict__ hC,
    int* __restrict__ rsR, int* __restrict__ rsC,
    const int* __restrict__ goffR, const int* __restrict__ goffC, int nbk)
{
    const int b = blockIdx.x;
    const bool isC = blockIdx.y;
    const int* h = (isC ? hC : hR);
    int* rs = (isC ? rsC : rsR);
    const int g0 = (isC ? goffC : goffR)[b];
    __shared__ int s[256];
    const int t = threadIdx.x;
    int v = h[(size_t)t * nbk + b];
    s[t] = v;
    __syncthreads();
#pragma unroll
    for (int d = 1; d < 256; d <<= 1) {
        int tv = (t >= d) ? s[t - d] : 0;
        __syncthreads();
        s[t] += tv;
        __syncthreads();
    }
    rs[(size_t)t * nbk + b] = g0 + s[t] - v;
}

// ---------------- K5: LDS-staged SORTED scatter, one grouping per block -----------
__global__ __launch_bounds__(256) void scatter_sorted(
    const int* __restrict__ rows, const int* __restrict__ cols,
    const float* __restrict__ vals,
    const int* __restrict__ hR, const int* __restrict__ rsR, int2* __restrict__ recR,
    const int* __restrict__ hC, const int* __restrict__ rsC, int2* __restrict__ recC,
    int nnz, int nbk, int ce)
{
    __shared__ int2 recL[LDSREC];
    __shared__ unsigned char bktL[LDSREC];
    __shared__ int lpos[NBKMAX], lcur[NBKMAX], lrs[NBKMAX], ssc[256];
    const int t = threadIdx.x;
    const int chunk = blockIdx.x;
    const bool isC = blockIdx.y;
    const int* h  = isC ? hC : hR;
    const int* rs = isC ? rsC : rsR;
    int2* recG    = isC ? recC : recR;
    const int e0 = chunk * ce, e1 = min(nnz, e0 + ce);
    const int Lc = e1 - e0;

    int v = (t < nbk) ? h[(size_t)chunk * nbk + t] : 0;
    if (t < nbk) lrs[t] = rs[(size_t)chunk * nbk + t];
    ssc[t] = v;
    __syncthreads();
#pragma unroll
    for (int d = 1; d < 256; d <<= 1) {
        int tv = (t >= d) ? ssc[t - d] : 0;
        __syncthreads();
        ssc[t] += tv;
        __syncthreads();
    }
    if (t < nbk) { lpos[t] = ssc[t] - v; lcur[t] = 0; }
    __syncthreads();

    for (int e = e0 + t; e < e1; e += 256) {
        int r = rows[e], c = cols[e];
        int dst  = isC ? c : r;
        int gcol = isC ? r : c;
        int b = dst >> 8;
        int q = atomicAdd(&lcur[b], 1);
        int slot = lpos[b] + q;
        recL[slot] = make_int2(((dst & 255) << 16) | gcol, __float_as_int(vals[e]));
        bktL[slot] = (unsigned char)b;
    }
    __syncthreads();

    for (int j = t; j < Lc; j += 256) {
        int b = bktL[j];
        recG[lrs[b] + (j - lpos[b])] = recL[j];
    }
}

// ---------------- per-bucket row sort -> packed 4B pairs ----------------
__global__ __launch_bounds__(256) void sort_buckets(
    const int2* __restrict__ recR, const int2* __restrict__ recC,
    const int* __restrict__ goffR, const int* __restrict__ cntR,
    const int* __restrict__ goffC, const int* __restrict__ cntC,
    unsigned* __restrict__ pairsR, unsigned* __restrict__ pairsC,
    int* __restrict__ offR, int* __restrict__ lenR,
    int* __restrict__ offC, int* __restrict__ lenC, int N)
{
    const bool isC = blockIdx.y;
    const int b = blockIdx.x;
    const int2* rec = isC ? recC : recR;
    unsigned* pairs = isC ? pairsC : pairsR;
    int* off = isC ? offC : offR;
    int* len = isC ? lenC : lenR;
    const int s = (isC ? goffC : goffR)[b];
    const int L = (isC ? cntC : cntR)[b];
    const int t = threadIdx.x;

    __shared__ int lcnt[RB], lpos[RB], lcur[RB], sscan[256];
    lcnt[t] = 0;
    __syncthreads();
    for (int i = t; i < L; i += 256)
        atomicAdd(&lcnt[rec[s + i].x >> 16], 1);
    __syncthreads();
    {
        int v = lcnt[t];
        sscan[t] = v;
        __syncthreads();
#pragma unroll
        for (int d = 1; d < 256; d <<= 1) {
            int tv = (t >= d) ? sscan[t - d] : 0;
            __syncthreads();
            sscan[t] += tv;
            __syncthreads();
        }
        lpos[t] = sscan[t] - v;
    }
    {
        int row = b * RB + t;
        if (row < N) { off[row] = s + lpos[t]; len[row] = lcnt[t]; }
        lcur[t] = 0;
    }
    __syncthreads();
    for (int i = t; i < L; i += 256) {
        int2 pr = rec[s + i];
        int r = pr.x >> 16;
        int p = lpos[r] + atomicAdd(&lcur[r], 1);
        unsigned vb = (unsigned)pr.y;
        unsigned v16 = (vb + 0x7FFFu + ((vb >> 16) & 1u)) >> 16;
        pairs[s + p] = (v16 << 16) | (unsigned)(pr.x & 0xFFFF);
    }
}

// ---------------- pairs-gather SpMM v4: 16 edges in flight ----------------
__global__ __launch_bounds__(256) void spmm_pairs_v4(
    const unsigned* __restrict__ pairs, const int* __restrict__ off,
    const int* __restrict__ len, const unsigned short* __restrict__ Xb,
    float* __restrict__ out, int N)
{
    const int row = (blockIdx.x * 256 + threadIdx.x) >> 6;
    if (row >= N) return;
    const int lane = threadIdx.x & 63;
    const int half = lane >> 5;
    const int cq = (lane & 31) << 2;
    const int s = off[row];
    const int L = len[row];

    float4 a0 = make_float4(0.f, 0.f, 0.f, 0.f);
    float4 a1 = make_float4(0.f, 0.f, 0.f, 0.f);
    float4 a2 = make_float4(0.f, 0.f, 0.f, 0.f);
    float4 a3 = make_float4(0.f, 0.f, 0.f, 0.f);

#define BF(u) __uint_as_float((unsigned)(u) << 16)
    int i = 0;
    for (; i + 15 < L; i += 16) {
        unsigned p0 = pairs[s + i + 0 + half];
        unsigned p1 = pairs[s + i + 2 + half];
        unsigned p2 = pairs[s + i + 4 + half];
        unsigned p3 = pairs[s + i + 6 + half];
        unsigned p4 = pairs[s + i + 8 + half];
        unsigned p5 = pairs[s + i + 10 + half];
        unsigned p6 = pairs[s + i + 12 + half];
        unsigned p7 = pairs[s + i + 14 + half];
        ushort4 x0 = *reinterpret_cast<const ushort4*>(&Xb[(size_t)(p0 & 0xFFFFu) * D + cq]);
        ushort4 x1 = *reinterpret_cast<const ushort4*>(&Xb[(size_t)(p1 & 0xFFFFu) * D + cq]);
        ushort4 x2 = *reinterpret_cast<const ushort4*>(&Xb[(size_t)(p2 & 0xFFFFu) * D + cq]);
        ushort4 x3 = *reinterpret_cast<const ushort4*>(&Xb[(size_t)(p3 & 0xFFFFu) * D + cq]);
        ushort4 x4 = *reinterpret_cast<const ushort4*>(&Xb[(size_t)(p4 & 0xFFFFu) * D + cq]);
        ushort4 x5 = *reinterpret_cast<const ushort4*>(&Xb[(size_t)(p5 & 0xFFFFu) * D + cq]);
        ushort4 x6 = *reinterpret_cast<const ushort4*>(&Xb[(size_t)(p6 & 0xFFFFu) * D + cq]);
        ushort4 x7 = *reinterpret_cast<const ushort4*>(&Xb[(size_t)(p7 & 0xFFFFu) * D + cq]);
        float v0 = __uint_as_float(p0 & 0xFFFF0000u);
        float v1 = __uint_as_float(p1 & 0xFFFF0000u);
        float v2 = __uint_as_float(p2 & 0xFFFF0000u);
        float v3 = __uint_as_float(p3 & 0xFFFF0000u);
        float v4 = __uint_as_float(p4 & 0xFFFF0000u);
        float v5 = __uint_as_float(p5 & 0xFFFF0000u);
        float v6 = __uint_as_float(p6 & 0xFFFF0000u);
        float v7 = __uint_as_float(p7 & 0xFFFF0000u);
        a0.x += v0 * BF(x0.x); a0.y += v0 * BF(x0.y); a0.z += v0 * BF(x0.z); a0.w += v0 * BF(x0.w);
        a1.x += v1 * BF(x1.x); a1.y += v1 * BF(x1.y); a1.z += v1 * BF(x1.z); a1.w += v1 * BF(x1.w);
        a2.x += v2 * BF(x2.x); a2.y += v2 * BF(x2.y); a2.z += v2 * BF(x2.z); a2.w += v2 * BF(x2.w);
        a3.x += v3 * BF(x3.x); a3.y += v3 * BF(x3.y); a3.z += v3 * BF(x3.z); a3.w += v3 * BF(x3.w);
        a0.x += v4 * BF(x4.x); a0.y += v4 * BF(x4.y); a0.z += v4 * BF(x4.z); a0.w += v4 * BF(x4.w);
        a1.x += v5 * BF(x5.x); a1.y += v5 * BF(x5.y); a1.z += v5 * BF(x5.z); a1.w += v5 * BF(x5.w);
        a2.x += v6 * BF(x6.x); a2.y += v6 * BF(x6.y); a2.z += v6 * BF(x6.z); a2.w += v6 * BF(x6.w);
        a3.x += v7 * BF(x7.x); a3.y += v7 * BF(x7.y); a3.z += v7 * BF(x7.z); a3.w += v7 * BF(x7.w);
    }
    for (; i + 7 < L; i += 8) {
        unsigned p0 = pairs[s + i + 0 + half];
        unsigned p1 = pairs[s + i + 2 + half];
        unsigned p2 = pairs[s + i + 4 + half];
        unsigned p3 = pairs[s + i + 6 + half];
        ushort4 x0 = *reinterpret_cast<const ushort4*>(&Xb[(size_t)(p0 & 0xFFFFu) * D + cq]);
        ushort4 x1 = *reinterpret_cast<const ushort4*>(&Xb[(size_t)(p1 & 0xFFFFu) * D + cq]);
        ushort4 x2 = *reinterpret_cast<const ushort4*>(&Xb[(size_t)(p2 & 0xFFFFu) * D + cq]);
        ushort4 x3 = *reinterpret_cast<const ushort4*>(&Xb[(size_t)(p3 & 0xFFFFu) * D + cq]);
        float v0 = __uint_as_float(p0 & 0xFFFF0000u);
        float v1 = __uint_as_float(p1 & 0xFFFF0000u);
        float v2 = __uint_as_float(p2 & 0xFFFF0000u);
        float v3 = __uint_as_float(p3 & 0xFFFF0000u);
        a0.x += v0 * BF(x0.x); a0.y += v0 * BF(x0.y); a0.z += v0 * BF(x0.z); a0.w += v0 * BF(x0.w);
        a1.x += v1 * BF(x1.x); a1.y += v1 * BF(x1.y); a1.z += v1 * BF(x1.z); a1.w += v1 * BF(x1.w);
        a2.x += v2 * BF(x2.x); a2.y += v2 * BF(x2.y); a2.z += v2 * BF(x2.z); a2.w += v2 * BF(x2.w);
        a3.x += v3 * BF(x3.x); a3.y += v3 * BF(x3.y); a3.z += v3 * BF(x3.z); a3.w += v3 * BF(x3.w);
    }
    for (; i < L; i += 2) {
        int e = i + half;
        unsigned p = (e < L) ? pairs[s + e] : 0u;
        ushort4 xv = *reinterpret_cast<const ushort4*>(&Xb[(size_t)(p & 0xFFFFu) * D + cq]);
        float v = __uint_as_float(p & 0xFFFF0000u);
        a0.x += v * BF(xv.x); a0.y += v * BF(xv.y); a0.z += v * BF(xv.z); a0.w += v * BF(xv.w);
    }
#undef BF

    float4 A;
    A.x = (a0.x + a1.x) + (a2.x + a3.x);
    A.y = (a0.y + a1.y) + (a2.y + a3.y);
    A.z = (a0.z + a1.z) + (a2.z + a3.z);
    A.w = (a0.w + a1.w) + (a2.w + a3.w);
    A.x += __shfl_xor(A.x, 32);
    A.y += __shfl_xor(A.y, 32);
    A.z += __shfl_xor(A.z, 32);
    A.w += __shfl_xor(A.w, 32);
    if (half == 0)
        *reinterpret_cast<float4*>(&out[(size_t)row * D + cq]) = A;
}

// ---------------- atomic fallback ----------------
__global__ __launch_bounds__(256) void spmm_atomic(
    const float* __restrict__ vals, const int* __restrict__ orow,
    const int* __restrict__ gcol, const float* __restrict__ Xm,
    float* __restrict__ outm, int nnz)
{
    const int gwave = (blockIdx.x * 256 + threadIdx.x) >> 6;
    const int lane = threadIdx.x & 63;
    const int e0 = gwave * 4;
#pragma unroll
    for (int i = 0; i < 4; ++i) {
        int e = e0 + i;
        if (e >= nnz) break;
        float v = vals[e];
        int r = orow[e];
        int c = gcol[e];
        float2 xv = *reinterpret_cast<const float2*>(&Xm[(size_t)c * D + lane * 2]);
        unsafeAtomicAdd(&outm[(size_t)r * D + lane * 2 + 0], v * xv.x);
        unsafeAtomicAdd(&outm[(size_t)r * D + lane * 2 + 1], v * xv.y);
    }
}

extern "C" void kernel_launch(void* const* d_in, const int* in_sizes, int n_in,
                              void* d_out, int out_size, void* d_ws, size_t ws_size,
                              hipStream_t stream) {
    const float* x      = (const float*)d_in[0];
    const float* y      = (const float*)d_in[1];
    const float* c      = (const float*)d_in[2];
    const float* b      = (const float*)d_in[3];
    const float* A_vals = (const float*)d_in[4];
    const int*   A_rows = (const int*)d_in[5];
    const int*   A_cols = (const int*)d_in[6];
    const float* Ukx_w  = (const float*)d_in[7];
    const float* Ukx_b  = (const float*)d_in[8];
    const float* Uky_w  = (const float*)d_in[9];
    const float* Uky_b  = (const float*)d_in[10];
    const float* tau    = (const float*)d_in[11];
    const float* Vky_w  = (const float*)d_in[12];
    const float* Vky_b  = (const float*)d_in[13];
    const float* Wkx_w  = (const float*)d_in[14];
    const float* Wkx_b  = (const float*)d_in[15];
    const float* Vkx_w  = (const float*)d_in[16];
    const float* Vkx_b  = (const float*)d_in[17];
    const float* sigma  = (const float*)d_in[18];

    const int N   = in_sizes[0] / D;        // 50000
    const int nnz = in_sizes[4];            // 1.6M
    const int nbk = (N + RB - 1) / RB;      // 196

    float* out_x = (float*)d_out;
    float* out_y = out_x + (size_t)N * D;

    const int gemm_grid = (N + 63) / 64;
    const int ggrid = (N + 3) / 4;
    const int ce = (nnz + CH - 1) / CH;

    // ws layout (as round 12)
    const size_t pool = (size_t)nnz;
    char* base = (char*)d_ws;
    float* tmp = (float*)base;
    int2* recR = (int2*)base;
    int2* recC = recR + pool;
    size_t region0 = (size_t)N * D * 4;
    if (2 * pool * 8 > region0) region0 = 2 * pool * 8;
    char* pers = base + region0;
    float* UkyT = (float*)pers;
    float* UkxT = UkyT + D * D;
    float* VkyT = UkxT + D * D;
    float* WcT  = VkyT + D * D;
    unsigned short* UkyB = (unsigned short*)(WcT + D * D);
    unsigned short* UkxB = UkyB + D * D;
    unsigned short* VkyB = UkxB + D * D;
    unsigned short* WcB  = VkyB + D * D;
    float* bc = (float*)(WcB + D * D);
    unsigned* pairsR = (unsigned*)(bc + D);
    unsigned* pairsC = pairsR + pool;
    int* cntR  = (int*)(pairsC + pool);
    int* cntC  = cntR + nbk;
    int* goffR = cntC + nbk;
    int* goffC = goffR + nbk;
    int* offR  = goffC + nbk;
    int* lenR  = offR + N;
    int* offC  = lenR + N;
    int* lenC  = offC + N;
    int* hR  = (int*)pairsR;
    int* hC  = hR + (size_t)CH * nbk;
    int* rsR = hC + (size_t)CH * nbk;
    int* rsC = rsR + (size_t)CH * nbk;

    unsigned short* uyb = (unsigned short*)out_y;
    unsigned short* zxb = (unsigned short*)tmp;

    size_t need = region0 + (4 * (size_t)D * D + D) * 4 + 4 * (size_t)D * D * 2
                + 2 * pool * 4 + (4 * (size_t)nbk + 4 * (size_t)N) * 4;
    bool alias_fits = (size_t)4 * CH * nbk * 4 <= pool * 4;

    setup_weights<<<8, 256, 0, stream>>>(Uky_w, Ukx_w, Vky_w, Vkx_w, Wkx_w,
                                         Vkx_b, Wkx_b, UkyT, UkxT, VkyT, WcT,
                                         UkyB, UkxB, VkyB, WcB, bc);

    if (N < 65536 && nbk <= NBKMAX && ws_size >= need && alias_fits && ce <= LDSREC) {
        // ---- radix-style build ----
        {
            dim3 g1(CH, 2);
            hist_chunks<<<g1, 256, 0, stream>>>(A_rows, A_cols, hR, hC, nnz, nbk, ce);
            dim3 g2(nbk, 2);
            bucket_tot<<<g2, 256, 0, stream>>>(hR, hC, cntR, cntC, nbk);
            scan_buckets<<<2, 256, 0, stream>>>(cntR, cntC, goffR, goffC, nbk);
            runstarts<<<g2, 256, 0, stream>>>(hR, hC, rsR, rsC, goffR, goffC, nbk);
            scatter_sorted<<<g1, 256, 0, stream>>>(A_rows, A_cols, A_vals,
                                                   hR, rsR, recR, hC, rsC, recC,
                                                   nnz, nbk, ce);
            sort_buckets<<<g2, 256, 0, stream>>>(recR, recC, goffR, cntR, goffC, cntC,
                                                 pairsR, pairsC, offR, lenR, offC, lenC, N);
        }

        // uy = y @ Uky^T + b  -> bf16 in out_y half (dead before y_new write)
        gemm_mfma<0, 1><<<gemm_grid, 256, 0, stream>>>(y, UkyB, Uky_b, nullptr, nullptr, nullptr,
                                                       (float*)uyb, N);
        // at_uy -> out_x
        spmm_pairs_v4<<<ggrid, 256, 0, stream>>>(pairsC, offC, lenC, uyb, out_x, N);
        // x_new -> out_x (in place) AND zx -> zxb (fused; records dead)
        gemm_mfma_xz<<<gemm_grid, 256, 0, stream>>>(x, UkxB, Ukx_b, c, out_x, tau, out_x,
                                                    WcB, bc, zxb, N);
        // az -> out_y
        spmm_pairs_v4<<<ggrid, 256, 0, stream>>>(pairsR, offR, lenR, zxb, out_y, N);
        // y_new -> out_y (in place)
        gemm_mfma<2, 0><<<gemm_grid, 256, 0, stream>>>(y, VkyB, Vky_b, b, out_y, sigma, out_y, N);
    } else {
        // ---- atomic fallback (all fp32) ----
        const int spmm_grid = (nnz + 15) / 16;
        gemm_v2<0><<<gemm_grid, 256, 0, stream>>>(y, UkyT, Uky_b, nullptr, nullptr, nullptr, tmp, N);
        hipMemsetAsync(out_x, 0, (size_t)N * D * sizeof(float), stream);
        spmm_atomic<<<spmm_grid, 256, 0, stream>>>(A_vals, A_cols, A_rows, tmp, out_x, nnz);
        gemm_v2<1><<<gemm_grid, 256, 0, stream>>>(x, UkxT, Ukx_b, c, out_x, tau, out_x, N);
        gemm_v2<0><<<gemm_grid, 256, 0, stream>>>(out_x, WcT, bc, nullptr, nullptr, nullptr, tmp, N);
        hipMemsetAsync(out_y, 0, (size_t)N * D * sizeof(float), stream);
        spmm_atomic<<<spmm_grid, 256, 0, stream>>>(A_vals, A_rows, A_cols, tmp, out_y, nnz);
        gemm_v2<2><<<gemm_grid, 256, 0, stream>>>(y, VkyT, Vky_b, b, out_y, sigma, out_y, N);
    }
}

// Round 14
// 277.042 us; speedup vs baseline: 1.0394x; 1.0394x over previous
//
#include <hip/hip_runtime.h>

#define D 128
#define RB 256          // rows per bucket
#define NBKMAX 256      // max buckets (N <= 65536)
#define CH 256          // edge chunks
#define LDSREC 6400     // max records staged per chunk

typedef __attribute__((ext_vector_type(4))) float f32x4;
typedef __attribute__((ext_vector_type(8))) short bf16x8;

__device__ __forceinline__ unsigned short bf16r(float f) {
    unsigned b = __float_as_uint(f);
    return (unsigned short)((b + 0x7FFFu + ((b >> 16) & 1u)) >> 16);
}

// ---------------- setup: fp32 WT (fallback) + bf16 Wb (MFMA path) -----------------
__global__ __launch_bounds__(256) void setup_weights(
    const float* __restrict__ Uky, const float* __restrict__ Ukx,
    const float* __restrict__ Vky, const float* __restrict__ Vkx,
    const float* __restrict__ Wkx, const float* __restrict__ Vkx_b,
    const float* __restrict__ Wkx_b,
    float* __restrict__ UkyT, float* __restrict__ UkxT,
    float* __restrict__ VkyT, float* __restrict__ WcT,
    unsigned short* __restrict__ UkyB, unsigned short* __restrict__ UkxB,
    unsigned short* __restrict__ VkyB, unsigned short* __restrict__ WcB,
    float* __restrict__ bc)
{
    const int m = blockIdx.x;
    if (m < 4) {
        const float* src = (m == 0) ? Uky : (m == 1) ? Ukx : (m == 2) ? Vky : nullptr;
        float* dst = (m == 0) ? UkyT : (m == 1) ? UkxT : (m == 2) ? VkyT : WcT;
        for (int i = threadIdx.x; i < D * D; i += 256) {
            int k = i >> 7, d = i & 127;
            float v;
            if (m == 3) v = Vkx[d * D + k] - 2.0f * Wkx[d * D + k];
            else        v = src[d * D + k];
            dst[i] = v;
        }
        if (m == 3 && threadIdx.x < D)
            bc[threadIdx.x] = Vkx_b[threadIdx.x] - 2.0f * Wkx_b[threadIdx.x];
    } else {
        const int mm = m - 4;
        const float* src = (mm == 0) ? Uky : (mm == 1) ? Ukx : (mm == 2) ? Vky : nullptr;
        unsigned short* dst = (mm == 0) ? UkyB : (mm == 1) ? UkxB : (mm == 2) ? VkyB : WcB;
        for (int i = threadIdx.x; i < D * D; i += 256) {
            float v;
            if (mm == 3) v = Vkx[i] - 2.0f * Wkx[i];
            else         v = src[i];
            dst[i] = bf16r(v);
        }
    }
}

// ---------------- MFMA GEMM (round 10, proven) ----------------
template <int EPI, int OB16>
__global__ __launch_bounds__(256) void gemm_mfma(
    const float* __restrict__ X, const unsigned short* __restrict__ Wb,
    const float* __restrict__ bias, const float* __restrict__ colvec,
    const float* __restrict__ spout, const float* __restrict__ scal,
    float* __restrict__ out, int N)
{
    __shared__ __align__(16) unsigned short Xs[64 * 128];
    const int t = threadIdx.x;
    const int block_row = blockIdx.x * 64;

#pragma unroll
    for (int i = 0; i < 8; ++i) {
        int f = t + i * 256;
        int r = f >> 5;
        int k4 = (f & 31) << 2;
        float4 g = make_float4(0.f, 0.f, 0.f, 0.f);
        int row = block_row + r;
        if (row < N) g = *reinterpret_cast<const float4*>(&X[(size_t)row * D + k4]);
        ushort4 h;
        h.x = bf16r(g.x); h.y = bf16r(g.y); h.z = bf16r(g.z); h.w = bf16r(g.w);
        unsigned byte = (unsigned)(k4 * 2) ^ ((unsigned)(r & 7) << 4);
        *reinterpret_cast<ushort4*>((char*)Xs + r * 256 + byte) = h;
    }
    __syncthreads();

    const int w  = t >> 6;
    const int l  = t & 63;
    const int lr = l & 15;
    const int lq = l >> 4;

    f32x4 acc[8];
#pragma unroll
    for (int nt = 0; nt < 8; ++nt) acc[nt] = (f32x4)(0.f);

    const int arow = w * 16 + lr;

#pragma unroll
    for (int kc = 0; kc < 4; ++kc) {
        unsigned abyte = ((unsigned)(kc * 64 + lq * 16)) ^ ((unsigned)(arow & 7) << 4);
        bf16x8 a = *reinterpret_cast<const bf16x8*>((const char*)Xs + arow * 256 + abyte);
#pragma unroll
        for (int nt = 0; nt < 8; ++nt) {
            bf16x8 b = *reinterpret_cast<const bf16x8*>(
                &Wb[(size_t)(nt * 16 + lr) * D + kc * 32 + lq * 8]);
            acc[nt] = __builtin_amdgcn_mfma_f32_16x16x32_bf16(a, b, acc[nt], 0, 0, 0);
        }
    }

    const float sc = (EPI == 0) ? 0.f : scal[0];
    float bs[8];
#pragma unroll
    for (int nt = 0; nt < 8; ++nt) bs[nt] = bias[nt * 16 + lr];

#pragma unroll
    for (int r = 0; r < 4; ++r) {
        const int row = block_row + w * 16 + lq * 4 + r;
        if (row >= N) continue;
        const float cv = (EPI == 0) ? 0.f : colvec[row];
#pragma unroll
        for (int nt = 0; nt < 8; ++nt) {
            const int col = nt * 16 + lr;
            float res = acc[nt][r] + bs[nt];
            if (EPI == 1) {
                float sp = spout[(size_t)row * D + col];
                res = fmaxf(res - sc * (cv - sp), 0.f);
            } else if (EPI == 2) {
                float sp = spout[(size_t)row * D + col];
                res = fmaxf(res - sc * (cv + sp), 0.f);
            }
            if (OB16) ((unsigned short*)out)[(size_t)row * D + col] = bf16r(res);
            else      out[(size_t)row * D + col] = res;
        }
    }
}

// ---------------- fp32 GEMM (fallback path only) ----------------
template <int EPI>
__global__ __launch_bounds__(256) void gemm_v2(
    const float* __restrict__ X, const float* __restrict__ WT,
    const float* __restrict__ bias, const float* __restrict__ colvec,
    const float* __restrict__ spout, const float* __restrict__ scal,
    float* __restrict__ out, int N)
{
    __shared__ float Xsf[64][D + 4];
    __shared__ float Wt[64][D + 4];
    const int t = threadIdx.x;
    const int block_row = blockIdx.x * 64;

#pragma unroll
    for (int i = 0; i < 8; ++i) {
        int f = t + i * 256;
        int r = f >> 5;
        int k4 = (f & 31) << 2;
        float4 g = make_float4(0.f, 0.f, 0.f, 0.f);
        int row = block_row + r;
        if (row < N) g = *reinterpret_cast<const float4*>(&X[(size_t)row * D + k4]);
        *reinterpret_cast<float4*>(&Xsf[r][k4]) = g;
    }

    const int cg = t & 15;
    const int rp = t >> 4;
    const int r0 = rp * 4;
    const int c0 = cg * 4, c1 = 64 + cg * 4;
    float acc[4][8] = {{0.f}};

    for (int kb = 0; kb < D; kb += 64) {
        __syncthreads();
#pragma unroll
        for (int i = 0; i < 8; ++i) {
            int f = t + i * 256;
            int kk = f >> 5;
            int d4 = (f & 31) << 2;
            float4 g = *reinterpret_cast<const float4*>(&WT[(size_t)(kb + kk) * D + d4]);
            *reinterpret_cast<float4*>(&Wt[kk][d4]) = g;
        }
        __syncthreads();
#pragma unroll 2
        for (int k4 = 0; k4 < 64; k4 += 4) {
            float4 xr[4];
#pragma unroll
            for (int j = 0; j < 4; ++j)
                xr[j] = *reinterpret_cast<const float4*>(&Xsf[r0 + j][kb + k4]);
#pragma unroll
            for (int q = 0; q < 4; ++q) {
                const float4 w0 = *reinterpret_cast<const float4*>(&Wt[k4 + q][c0]);
                const float4 w1 = *reinterpret_cast<const float4*>(&Wt[k4 + q][c1]);
#pragma unroll
                for (int j = 0; j < 4; ++j) {
                    const float xv = (q == 0) ? xr[j].x : (q == 1) ? xr[j].y
                                   : (q == 2) ? xr[j].z : xr[j].w;
                    acc[j][0] += xv * w0.x; acc[j][1] += xv * w0.y;
                    acc[j][2] += xv * w0.z; acc[j][3] += xv * w0.w;
                    acc[j][4] += xv * w1.x; acc[j][5] += xv * w1.y;
                    acc[j][6] += xv * w1.z; acc[j][7] += xv * w1.w;
                }
            }
        }
    }

    const float sc = (EPI == 0) ? 0.f : scal[0];
    const float4 bias0 = *reinterpret_cast<const float4*>(&bias[c0]);
    const float4 bias1 = *reinterpret_cast<const float4*>(&bias[c1]);

#pragma unroll
    for (int j = 0; j < 4; ++j) {
        const int row = block_row + r0 + j;
        if (row >= N) continue;
        const float cv = (EPI == 0) ? 0.f : colvec[row];
#pragma unroll
        for (int h = 0; h < 2; ++h) {
            const int col = (h == 0) ? c0 : c1;
            const float4 bsv = (h == 0) ? bias0 : bias1;
            float4 res;
            res.x = acc[j][h * 4 + 0] + bsv.x;
            res.y = acc[j][h * 4 + 1] + bsv.y;
            res.z = acc[j][h * 4 + 2] + bsv.z;
            res.w = acc[j][h * 4 + 3] + bsv.w;
            if (EPI == 1) {
                float4 sp = *reinterpret_cast<const float4*>(&spout[(size_t)row * D + col]);
                res.x = fmaxf(res.x - sc * (cv - sp.x), 0.f);
                res.y = fmaxf(res.y - sc * (cv - sp.y), 0.f);
                res.z = fmaxf(res.z - sc * (cv - sp.z), 0.f);
                res.w = fmaxf(res.w - sc * (cv - sp.w), 0.f);
            } else if (EPI == 2) {
                float4 sp = *reinterpret_cast<const float4*>(&spout[(size_t)row * D + col]);
                res.x = fmaxf(res.x - sc * (cv + sp.x), 0.f);
                res.y = fmaxf(res.y - sc * (cv + sp.y), 0.f);
                res.z = fmaxf(res.z - sc * (cv + sp.z), 0.f);
                res.w = fmaxf(res.w - sc * (cv + sp.w), 0.f);
            }
            *reinterpret_cast<float4*>(&out[(size_t)row * D + col]) = res;
        }
    }
}

// ---------------- K1: per-chunk bucket histogram ----------------
__global__ __launch_bounds__(256) void hist_chunks(
    const int* __restrict__ rows, const int* __restrict__ cols,
    int* __restrict__ hR, int* __restrict__ hC, int nnz, int nbk, int ce)
{
    __shared__ int lh[NBKMAX];
    const int chunk = blockIdx.x;
    const bool isC = blockIdx.y;
    const int* idx = isC ? cols : rows;
    int* hout = (isC ? hC : hR) + (size_t)chunk * nbk;
    for (int i = threadIdx.x; i < nbk; i += 256) lh[i] = 0;
    __syncthreads();
    const int e0 = chunk * ce, e1 = min(nnz, e0 + ce);
    for (int e = e0 + threadIdx.x; e < e1; e += 256)
        atomicAdd(&lh[idx[e] >> 8], 1);
    __syncthreads();
    for (int i = threadIdx.x; i < nbk; i += 256) hout[i] = lh[i];
}

// ---------------- K2: per-bucket chunk prefix + totals (merged bucket_tot) --------
// rs'[c][b] = prefix_{c'<c} h[c'][b]  (goff added later by scatter); cnt[b] = total
__global__ __launch_bounds__(256) void runstarts_tot(
    const int* __restrict__ hR, const int* __restrict__ hC,
    int* __restrict__ rsR, int* __restrict__ rsC,
    int* __restrict__ cntR, int* __restrict__ cntC, int nbk)
{
    const int b = blockIdx.x;
    const bool isC = blockIdx.y;
    const int* h = (isC ? hC : hR);
    int* rs  = (isC ? rsC : rsR);
    int* cnt = (isC ? cntC : cntR);
    __shared__ int s[256];
    const int t = threadIdx.x;
    int v = h[(size_t)t * nbk + b];
    s[t] = v;
    __syncthreads();
#pragma unroll
    for (int d = 1; d < 256; d <<= 1) {
        int tv = (t >= d) ? s[t - d] : 0;
        __syncthreads();
        s[t] += tv;
        __syncthreads();
    }
    rs[(size_t)t * nbk + b] = s[t] - v;
    if (t == 255) cnt[b] = s[255];
}

// ---------------- K3: bucket scan -> goff ----------------
__global__ __launch_bounds__(256) void scan_buckets(
    const int* __restrict__ cntR, const int* __restrict__ cntC,
    int* __restrict__ goffR, int* __restrict__ goffC, int nbk)
{
    const int* cnt = blockIdx.x ? cntC : cntR;
    int* goff = blockIdx.x ? goffC : goffR;
    __shared__ int s[256];
    const int t = threadIdx.x;
    int v = (t < nbk) ? cnt[t] : 0;
    s[t] = v;
    __syncthreads();
#pragma unroll
    for (int d = 1; d < 256; d <<= 1) {
        int tv = (t >= d) ? s[t - d] : 0;
        __syncthreads();
        s[t] += tv;
        __syncthreads();
    }
    if (t < nbk) goff[t] = s[t] - v;
}

// ---------------- K4: LDS-staged SORTED scatter, one grouping per block -----------
// record = { (dest%256)<<16 | gather_col , val_bits }  (needs N < 65536)
__global__ __launch_bounds__(256) void scatter_sorted(
    const int* __restrict__ rows, const int* __restrict__ cols,
    const float* __restrict__ vals,
    const int* __restrict__ hR, const int* __restrict__ rsR,
    const int* __restrict__ goffR, int2* __restrict__ recR,
    const int* __restrict__ hC, const int* __restrict__ rsC,
    const int* __restrict__ goffC, int2* __restrict__ recC,
    int nnz, int nbk, int ce)
{
    __shared__ int2 recL[LDSREC];
    __shared__ unsigned char bktL[LDSREC];
    __shared__ int lpos[NBKMAX], lcur[NBKMAX], lrs[NBKMAX], ssc[256];
    const int t = threadIdx.x;
    const int chunk = blockIdx.x;
    const bool isC = blockIdx.y;
    const int* h    = isC ? hC : hR;
    const int* rs   = isC ? rsC : rsR;
    const int* goff = isC ? goffC : goffR;
    int2* recG      = isC ? recC : recR;
    const int e0 = chunk * ce, e1 = min(nnz, e0 + ce);
    const int Lc = e1 - e0;

    int v = (t < nbk) ? h[(size_t)chunk * nbk + t] : 0;
    if (t < nbk) lrs[t] = rs[(size_t)chunk * nbk + t] + goff[t];
    ssc[t] = v;
    __syncthreads();
#pragma unroll
    for (int d = 1; d < 256; d <<= 1) {
        int tv = (t >= d) ? ssc[t - d] : 0;
        __syncthreads();
        ssc[t] += tv;
        __syncthreads();
    }
    if (t < nbk) { lpos[t] = ssc[t] - v; lcur[t] = 0; }
    __syncthreads();

    for (int e = e0 + t; e < e1; e += 256) {
        int r = rows[e], c = cols[e];
        int dst  = isC ? c : r;
        int gcol = isC ? r : c;
        int b = dst >> 8;
        int q = atomicAdd(&lcur[b], 1);
        int slot = lpos[b] + q;
        recL[slot] = make_int2(((dst & 255) << 16) | gcol, __float_as_int(vals[e]));
        bktL[slot] = (unsigned char)b;
    }
    __syncthreads();

    for (int j = t; j < Lc; j += 256) {
        int b = bktL[j];
        recG[lrs[b] + (j - lpos[b])] = recL[j];
    }
}

// ---------------- per-bucket row sort -> packed 4B pairs ----------------
__global__ __launch_bounds__(256) void sort_buckets(
    const int2* __restrict__ recR, const int2* __restrict__ recC,
    const int* __restrict__ goffR, const int* __restrict__ cntR,
    const int* __restrict__ goffC, const int* __restrict__ cntC,
    unsigned* __restrict__ pairsR, unsigned* __restrict__ pairsC,
    int* __restrict__ offR, int* __restrict__ lenR,
    int* __restrict__ offC, int* __restrict__ lenC, int N)
{
    const bool isC = blockIdx.y;
    const int b = blockIdx.x;
    const int2* rec = isC ? recC : recR;
    unsigned* pairs = isC ? pairsC : pairsR;
    int* off = isC ? offC : offR;
    int* len = isC ? lenC : lenR;
    const int s = (isC ? goffC : goffR)[b];
    const int L = (isC ? cntC : cntR)[b];
    const int t = threadIdx.x;

    __shared__ int lcnt[RB], lpos[RB], lcur[RB], sscan[256];
    lcnt[t] = 0;
    __syncthreads();
    for (int i = t; i < L; i += 256)
        atomicAdd(&lcnt[rec[s + i].x >> 16], 1);
    __syncthreads();
    {
        int v = lcnt[t];
        sscan[t] = v;
        __syncthreads();
#pragma unroll
        for (int d = 1; d < 256; d <<= 1) {
            int tv = (t >= d) ? sscan[t - d] : 0;
            __syncthreads();
            sscan[t] += tv;
            __syncthreads();
        }
        lpos[t] = sscan[t] - v;
    }
    {
        int row = b * RB + t;
        if (row < N) { off[row] = s + lpos[t]; len[row] = lcnt[t]; }
        lcur[t] = 0;
    }
    __syncthreads();
    for (int i = t; i < L; i += 256) {
        int2 pr = rec[s + i];
        int r = pr.x >> 16;
        int p = lpos[r] + atomicAdd(&lcur[r], 1);
        unsigned vb = (unsigned)pr.y;
        unsigned v16 = (vb + 0x7FFFu + ((vb >> 16) & 1u)) >> 16;
        pairs[s + p] = (v16 << 16) | (unsigned)(pr.x & 0xFFFF);
    }
}

// ---------------- pairs-gather SpMM v4: 16 edges in flight ----------------
__global__ __launch_bounds__(256) void spmm_pairs_v4(
    const unsigned* __restrict__ pairs, const int* __restrict__ off,
    const int* __restrict__ len, const unsigned short* __restrict__ Xb,
    float* __restrict__ out, int N)
{
    const int row = (blockIdx.x * 256 + threadIdx.x) >> 6;
    if (row >= N) return;
    const int lane = threadIdx.x & 63;
    const int half = lane >> 5;
    const int cq = (lane & 31) << 2;
    const int s = off[row];
    const int L = len[row];

    float4 a0 = make_float4(0.f, 0.f, 0.f, 0.f);
    float4 a1 = make_float4(0.f, 0.f, 0.f, 0.f);
    float4 a2 = make_float4(0.f, 0.f, 0.f, 0.f);
    float4 a3 = make_float4(0.f, 0.f, 0.f, 0.f);

#define BF(u) __uint_as_float((unsigned)(u) << 16)
    int i = 0;
    for (; i + 15 < L; i += 16) {
        unsigned p0 = pairs[s + i + 0 + half];
        unsigned p1 = pairs[s + i + 2 + half];
        unsigned p2 = pairs[s + i + 4 + half];
        unsigned p3 = pairs[s + i + 6 + half];
        unsigned p4 = pairs[s + i + 8 + half];
        unsigned p5 = pairs[s + i + 10 + half];
        unsigned p6 = pairs[s + i + 12 + half];
        unsigned p7 = pairs[s + i + 14 + half];
        ushort4 x0 = *reinterpret_cast<const ushort4*>(&Xb[(size_t)(p0 & 0xFFFFu) * D + cq]);
        ushort4 x1 = *reinterpret_cast<const ushort4*>(&Xb[(size_t)(p1 & 0xFFFFu) * D + cq]);
        ushort4 x2 = *reinterpret_cast<const ushort4*>(&Xb[(size_t)(p2 & 0xFFFFu) * D + cq]);
        ushort4 x3 = *reinterpret_cast<const ushort4*>(&Xb[(size_t)(p3 & 0xFFFFu) * D + cq]);
        ushort4 x4 = *reinterpret_cast<const ushort4*>(&Xb[(size_t)(p4 & 0xFFFFu) * D + cq]);
        ushort4 x5 = *reinterpret_cast<const ushort4*>(&Xb[(size_t)(p5 & 0xFFFFu) * D + cq]);
        ushort4 x6 = *reinterpret_cast<const ushort4*>(&Xb[(size_t)(p6 & 0xFFFFu) * D + cq]);
        ushort4 x7 = *reinterpret_cast<const ushort4*>(&Xb[(size_t)(p7 & 0xFFFFu) * D + cq]);
        float v0 = __uint_as_float(p0 & 0xFFFF0000u);
        float v1 = __uint_as_float(p1 & 0xFFFF0000u);
        float v2 = __uint_as_float(p2 & 0xFFFF0000u);
        float v3 = __uint_as_float(p3 & 0xFFFF0000u);
        float v4 = __uint_as_float(p4 & 0xFFFF0000u);
        float v5 = __uint_as_float(p5 & 0xFFFF0000u);
        float v6 = __uint_as_float(p6 & 0xFFFF0000u);
        float v7 = __uint_as_float(p7 & 0xFFFF0000u);
        a0.x += v0 * BF(x0.x); a0.y += v0 * BF(x0.y); a0.z += v0 * BF(x0.z); a0.w += v0 * BF(x0.w);
        a1.x += v1 * BF(x1.x); a1.y += v1 * BF(x1.y); a1.z += v1 * BF(x1.z); a1.w += v1 * BF(x1.w);
        a2.x += v2 * BF(x2.x); a2.y += v2 * BF(x2.y); a2.z += v2 * BF(x2.z); a2.w += v2 * BF(x2.w);
        a3.x += v3 * BF(x3.x); a3.y += v3 * BF(x3.y); a3.z += v3 * BF(x3.z); a3.w += v3 * BF(x3.w);
        a0.x += v4 * BF(x4.x); a0.y += v4 * BF(x4.y); a0.z += v4 * BF(x4.z); a0.w += v4 * BF(x4.w);
        a1.x += v5 * BF(x5.x); a1.y += v5 * BF(x5.y); a1.z += v5 * BF(x5.z); a1.w += v5 * BF(x5.w);
        a2.x += v6 * BF(x6.x); a2.y += v6 * BF(x6.y); a2.z += v6 * BF(x6.z); a2.w += v6 * BF(x6.w);
        a3.x += v7 * BF(x7.x); a3.y += v7 * BF(x7.y); a3.z += v7 * BF(x7.z); a3.w += v7 * BF(x7.w);
    }
    for (; i + 7 < L; i += 8) {
        unsigned p0 = pairs[s + i + 0 + half];
        unsigned p1 = pairs[s + i + 2 + half];
        unsigned p2 = pairs[s + i + 4 + half];
        unsigned p3 = pairs[s + i + 6 + half];
        ushort4 x0 = *reinterpret_cast<const ushort4*>(&Xb[(size_t)(p0 & 0xFFFFu) * D + cq]);
        ushort4 x1 = *reinterpret_cast<const ushort4*>(&Xb[(size_t)(p1 & 0xFFFFu) * D + cq]);
        ushort4 x2 = *reinterpret_cast<const ushort4*>(&Xb[(size_t)(p2 & 0xFFFFu) * D + cq]);
        ushort4 x3 = *reinterpret_cast<const ushort4*>(&Xb[(size_t)(p3 & 0xFFFFu) * D + cq]);
        float v0 = __uint_as_float(p0 & 0xFFFF0000u);
        float v1 = __uint_as_float(p1 & 0xFFFF0000u);
        float v2 = __uint_as_float(p2 & 0xFFFF0000u);
        float v3 = __uint_as_float(p3 & 0xFFFF0000u);
        a0.x += v0 * BF(x0.x); a0.y += v0 * BF(x0.y); a0.z += v0 * BF(x0.z); a0.w += v0 * BF(x0.w);
        a1.x += v1 * BF(x1.x); a1.y += v1 * BF(x1.y); a1.z += v1 * BF(x1.z); a1.w += v1 * BF(x1.w);
        a2.x += v2 * BF(x2.x); a2.y += v2 * BF(x2.y); a2.z += v2 * BF(x2.z); a2.w += v2 * BF(x2.w);
        a3.x += v3 * BF(x3.x); a3.y += v3 * BF(x3.y); a3.z += v3 * BF(x3.z); a3.w += v3 * BF(x3.w);
    }
    for (; i < L; i += 2) {
        int e = i + half;
        unsigned p = (e < L) ? pairs[s + e] : 0u;
        ushort4 xv = *reinterpret_cast<const ushort4*>(&Xb[(size_t)(p & 0xFFFFu) * D + cq]);
        float v = __uint_as_float(p & 0xFFFF0000u);
        a0.x += v * BF(xv.x); a0.y += v * BF(xv.y); a0.z += v * BF(xv.z); a0.w += v * BF(xv.w);
    }
#undef BF

    float4 A;
    A.x = (a0.x + a1.x) + (a2.x + a3.x);
    A.y = (a0.y + a1.y) + (a2.y + a3.y);
    A.z = (a0.z + a1.z) + (a2.z + a3.z);
    A.w = (a0.w + a1.w) + (a2.w + a3.w);
    A.x += __shfl_xor(A.x, 32);
    A.y += __shfl_xor(A.y, 32);
    A.z += __shfl_xor(A.z, 32);
    A.w += __shfl_xor(A.w, 32);
    if (half == 0)
        *reinterpret_cast<float4*>(&out[(size_t)row * D + cq]) = A;
}

// ---------------- atomic fallback ----------------
__global__ __launch_bounds__(256) void spmm_atomic(
    const float* __restrict__ vals, const int* __restrict__ orow,
    const int* __restrict__ gcol, const float* __restrict__ Xm,
    float* __restrict__ outm, int nnz)
{
    const int gwave = (blockIdx.x * 256 + threadIdx.x) >> 6;
    const int lane = threadIdx.x & 63;
    const int e0 = gwave * 4;
#pragma unroll
    for (int i = 0; i < 4; ++i) {
        int e = e0 + i;
        if (e >= nnz) break;
        float v = vals[e];
        int r = orow[e];
        int c = gcol[e];
        float2 xv = *reinterpret_cast<const float2*>(&Xm[(size_t)c * D + lane * 2]);
        unsafeAtomicAdd(&outm[(size_t)r * D + lane * 2 + 0], v * xv.x);
        unsafeAtomicAdd(&outm[(size_t)r * D + lane * 2 + 1], v * xv.y);
    }
}

extern "C" void kernel_launch(void* const* d_in, const int* in_sizes, int n_in,
                              void* d_out, int out_size, void* d_ws, size_t ws_size,
                              hipStream_t stream) {
    const float* x      = (const float*)d_in[0];
    const float* y      = (const float*)d_in[1];
    const float* c      = (const float*)d_in[2];
    const float* b      = (const float*)d_in[3];
    const float* A_vals = (const float*)d_in[4];
    const int*   A_rows = (const int*)d_in[5];
    const int*   A_cols = (const int*)d_in[6];
    const float* Ukx_w  = (const float*)d_in[7];
    const float* Ukx_b  = (const float*)d_in[8];
    const float* Uky_w  = (const float*)d_in[9];
    const float* Uky_b  = (const float*)d_in[10];
    const float* tau    = (const float*)d_in[11];
    const float* Vky_w  = (const float*)d_in[12];
    const float* Vky_b  = (const float*)d_in[13];
    const float* Wkx_w  = (const float*)d_in[14];
    const float* Wkx_b  = (const float*)d_in[15];
    const float* Vkx_w  = (const float*)d_in[16];
    const float* Vkx_b  = (const float*)d_in[17];
    const float* sigma  = (const float*)d_in[18];

    const int N   = in_sizes[0] / D;        // 50000
    const int nnz = in_sizes[4];            // 1.6M
    const int nbk = (N + RB - 1) / RB;      // 196

    float* out_x = (float*)d_out;
    float* out_y = out_x + (size_t)N * D;

    const int gemm_grid = (N + 63) / 64;
    const int ggrid = (N + 3) / 4;
    const int ce = (nnz + CH - 1) / CH;

    // ws layout (as round 12)
    const size_t pool = (size_t)nnz;
    char* base = (char*)d_ws;
    float* tmp = (float*)base;
    int2* recR = (int2*)base;
    int2* recC = recR + pool;
    size_t region0 = (size_t)N * D * 4;
    if (2 * pool * 8 > region0) region0 = 2 * pool * 8;
    char* pers = base + region0;
    float* UkyT = (float*)pers;
    float* UkxT = UkyT + D * D;
    float* VkyT = UkxT + D * D;
    float* WcT  = VkyT + D * D;
    unsigned short* UkyB = (unsigned short*)(WcT + D * D);
    unsigned short* UkxB = UkyB + D * D;
    unsigned short* VkyB = UkxB + D * D;
    unsigned short* WcB  = VkyB + D * D;
    float* bc = (float*)(WcB + D * D);
    unsigned* pairsR = (unsigned*)(bc + D);
    unsigned* pairsC = pairsR + pool;
    int* cntR  = (int*)(pairsC + pool);
    int* cntC  = cntR + nbk;
    int* goffR = cntC + nbk;
    int* goffC = goffR + nbk;
    int* offR  = goffC + nbk;
    int* lenR  = offR + N;
    int* offC  = lenR + N;
    int* lenC  = offC + N;
    int* hR  = (int*)pairsR;                 // alias: 4*CH*nbk ints in pairs region
    int* hC  = hR + (size_t)CH * nbk;
    int* rsR = hC + (size_t)CH * nbk;
    int* rsC = rsR + (size_t)CH * nbk;

    unsigned short* uyb = (unsigned short*)out_y;
    unsigned short* zxb = (unsigned short*)tmp;

    size_t need = region0 + (4 * (size_t)D * D + D) * 4 + 4 * (size_t)D * D * 2
                + 2 * pool * 4 + (4 * (size_t)nbk + 4 * (size_t)N) * 4;
    bool alias_fits = (size_t)4 * CH * nbk * 4 <= pool * 4;

    setup_weights<<<8, 256, 0, stream>>>(Uky_w, Ukx_w, Vky_w, Vkx_w, Wkx_w,
                                         Vkx_b, Wkx_b, UkyT, UkxT, VkyT, WcT,
                                         UkyB, UkxB, VkyB, WcB, bc);

    if (N < 65536 && nbk <= NBKMAX && ws_size >= need && alias_fits && ce <= LDSREC) {
        // ---- radix-style build (5 kernels) ----
        {
            dim3 g1(CH, 2);
            dim3 g2(nbk, 2);
            hist_chunks<<<g1, 256, 0, stream>>>(A_rows, A_cols, hR, hC, nnz, nbk, ce);
            runstarts_tot<<<g2, 256, 0, stream>>>(hR, hC, rsR, rsC, cntR, cntC, nbk);
            scan_buckets<<<2, 256, 0, stream>>>(cntR, cntC, goffR, goffC, nbk);
            scatter_sorted<<<g1, 256, 0, stream>>>(A_rows, A_cols, A_vals,
                                                   hR, rsR, goffR, recR,
                                                   hC, rsC, goffC, recC,
                                                   nnz, nbk, ce);
            sort_buckets<<<g2, 256, 0, stream>>>(recR, recC, goffR, cntR, goffC, cntC,
                                                 pairsR, pairsC, offR, lenR, offC, lenC, N);
        }

        // uy = y @ Uky^T + b  -> bf16 in out_y half (dead before y_new write)
        gemm_mfma<0, 1><<<gemm_grid, 256, 0, stream>>>(y, UkyB, Uky_b, nullptr, nullptr, nullptr,
                                                       (float*)uyb, N);
        // at_uy -> out_x
        spmm_pairs_v4<<<ggrid, 256, 0, stream>>>(pairsC, offC, lenC, uyb, out_x, N);
        // x_new -> out_x (in place)
        gemm_mfma<1, 0><<<gemm_grid, 256, 0, stream>>>(x, UkxB, Ukx_b, c, out_x, tau, out_x, N);
        // zx -> bf16 in tmp (records dead)
        gemm_mfma<0, 1><<<gemm_grid, 256, 0, stream>>>(out_x, WcB, bc, nullptr, nullptr, nullptr,
                                                       (float*)zxb, N);
        // az -> out_y
        spmm_pairs_v4<<<ggrid, 256, 0, stream>>>(pairsR, offR, lenR, zxb, out_y, N);
        // y_new -> out_y (in place)
        gemm_mfma<2, 0><<<gemm_grid, 256, 0, stream>>>(y, VkyB, Vky_b, b, out_y, sigma, out_y, N);
    } else {
        // ---- atomic fallback (all fp32) ----
        const int spmm_grid = (nnz + 15) / 16;
        gemm_v2<0><<<gemm_grid, 256, 0, stream>>>(y, UkyT, Uky_b, nullptr, nullptr, nullptr, tmp, N);
        hipMemsetAsync(out_x, 0, (size_t)N * D * sizeof(float), stream);
        spmm_atomic<<<spmm_grid, 256, 0, stream>>>(A_vals, A_cols, A_rows, tmp, out_x, nnz);
        gemm_v2<1><<<gemm_grid, 256, 0, stream>>>(x, UkxT, Ukx_b, c, out_x, tau, out_x, N);
        gemm_v2<0><<<gemm_grid, 256, 0, stream>>>(out_x, WcT, bc, nullptr, nullptr, nullptr, tmp, N);
        hipMemsetAsync(out_y, 0, (size_t)N * D * sizeof(float), stream);
        spmm_atomic<<<spmm_grid, 256, 0, stream>>>(A_vals, A_rows, A_cols, tmp, out_y, nnz);
        gemm_v2<2><<<gemm_grid, 256, 0, stream>>>(y, VkyT, Vky_b, b, out_y, sigma, out_y, N);
    }
}